// Round 11
// baseline (152.802 us; speedup 1.0000x reference)
//
#include <hip/hip_runtime.h>
#include <math.h>

#define NQ 12
#define DIM 4096
#define NL 6
#define TPB 256

typedef float f2 __attribute__((ext_vector_type(2)));

// ---------------------------------------------------------------------------
// R11 = R10 with the compile fix (sincosf into scalar locals, not &vec.y).
// Structure: R9's occupancy push (state is the ONLY LDS: 32768 B -> 5
// blocks/CU) + R8's precise trig. The 20 wave-uniform angles per layer
// (12 RY + 4 phi-phasors + 4 om-phasors) are sincosf'd one-per-lane and
// broadcast via __shfl; only wA/wC (thread-dependent diagonal phase) are
// per-thread sincosf (2/layer). R9's native __sinf/__cosf failed absmax
// (1.95e-2 vs 1.93e-2 threshold) — precise trig is mandatory.
//
// Everything else verified R5/R7/R8: logical-basis state, CNOT block =
// label->gray(label) folded into pass-C store addresses, phys14/phys15
// GF(2) bank swizzles, 3 passes/layer (label bits 0-3/4-7/8-11 = wires
// 11-8/7-4/3-0), last-layer D_om skipped, epilogue signs wire0=j3,
// wire1=j2^j3.
// ---------------------------------------------------------------------------

__device__ __forceinline__ f2 pk_mul(f2 a, f2 b) {
  f2 d; asm("v_pk_mul_f32 %0, %1, %2" : "=v"(d) : "v"(a), "v"(b)); return d;
}
__device__ __forceinline__ f2 pk_fma(f2 a, f2 b, f2 c) {
  f2 d; asm("v_pk_fma_f32 %0, %1, %2, %3" : "=v"(d) : "v"(a), "v"(b), "v"(c)); return d;
}
// complex mul, both operands packed (re,im)  [verified R8]
__device__ __forceinline__ f2 cmulp(f2 a, f2 c) {
  f2 r1, d;
  asm("v_pk_mul_f32 %0, %1, %2 op_sel:[0,0] op_sel_hi:[0,1]"
      : "=v"(r1) : "v"(a), "v"(c));
  asm("v_pk_fma_f32 %0, %1, %2, %3 op_sel:[1,1,0] op_sel_hi:[1,0,1] neg_lo:[1,0,0]"
      : "=v"(d) : "v"(a), "v"(c), "v"(r1));
  return d;
}
__device__ __forceinline__ f2 cj(f2 a) { return (f2){a.x, -a.y}; }

// RY pair update: a' = c*a - s*b ; b' = s*a + c*b  [verified R8]
template<int BIT>
__device__ __forceinline__ void apply_ry16(f2 v[16], f2 cc, f2 ss) {
  #pragma unroll
  for (int j = 0; j < 16; ++j) {
    if (j & (1 << BIT)) continue;
    const int k = j | (1 << BIT);
    f2 a = v[j], b = v[k];
    f2 t1 = pk_mul(a, cc);
    f2 t2 = pk_mul(a, ss);
    f2 na; asm("v_pk_fma_f32 %0, %1, %2, %3 neg_lo:[1,0,0] neg_hi:[1,0,0]"
               : "=v"(na) : "v"(b), "v"(ss), "v"(t1));
    f2 nb = pk_fma(b, cc, t2);
    v[j] = na; v[k] = nb;
  }
}

__global__ __launch_bounds__(TPB, 5)
void qsim12_kernel(const float* __restrict__ x, const float* __restrict__ w,
                   float* __restrict__ out) {
  __shared__ __align__(16) float st[2*DIM];   // exactly 32 KB — sole LDS use

  const int t = threadIdx.x;
  const int b = blockIdx.x;
  char* stb = (char*)st;
  const int lane = t & 63;

  // Precomputed byte-address bases (verified R5/R7).
  int baseA[8], baseB[8];
  #pragma unroll
  for (int m = 0; m < 8; ++m) {
    baseA[m] = (t << 7) + (((2*m) ^ (t & 14)) << 3);                 // phys14, A b128
    baseB[m] = ((t >> 4) << 11) + ((((t & 15) ^ (2*m))) << 3);       // + j*128
  }
  const int baseC = ((t >> 4) << 7) + ((((t & 15) ^ ((t >> 4) & 15))) << 3);  // + j*2048
  const int G = t ^ (t >> 1);
  int baseS[2];
  #pragma unroll
  for (int par = 0; par < 2; ++par) {
    const int k8 = par << 3;
    baseS[par] = ((((G >> 4) & 15) ^ k8) << 7)
               + ((((G & 15) ^ ((G >> 4) & 14) ^ k8)) << 3);
  }
  // per-thread diagonal signs (0.5 factor folded in)
  float sg[8];
  #pragma unroll
  for (int k = 0; k < 8; ++k) sg[k] = ((t >> k) & 1) ? 0.5f : -0.5f;

  f2 v[16];

  // ---- Init: amp(label) = prod_w (bit? sin:cos) * (-i)^popcount(label).
  // Pass-A ownership: label = t*16+j. Precise sincosf (12, once per thread).
  {
    float cw[NQ], sw[NQ];
    #pragma unroll
    for (int q = 0; q < NQ; ++q) {
      float xv = 0.5f * x[b*NQ + q];
      sincosf(xv, &sw[q], &cw[q]);
    }
    float rhi = 1.f;
    #pragma unroll
    for (int k = 0; k < 8; ++k)
      rhi *= ((t >> k) & 1) ? sw[7-k] : cw[7-k];
    const int popt = __popc(t);
    #pragma unroll
    for (int j = 0; j < 16; ++j) {
      float r = rhi;
      #pragma unroll
      for (int m = 0; m < 4; ++m)
        r *= ((j >> m) & 1) ? sw[11-m] : cw[11-m];
      const int pj = (popt + __popc(j)) & 3;
      if      (pj == 0) v[j] = (f2){ r, 0.f};
      else if (pj == 1) v[j] = (f2){0.f, -r};
      else if (pj == 2) v[j] = (f2){-r, 0.f};
      else              v[j] = (f2){0.f,  r};
    }
  }

  // broadcast slot -> packed phasor / RY coeffs (cv_s,sv_s computed per layer)
  #define BC(S)  (f2){ __shfl(cv_s, (S)), __shfl(sv_s, (S)) }
  #define RYG(BIT, WQ)                                                \
    { float c = __shfl(cv_s, (WQ)), s = __shfl(sv_s, (WQ));           \
      apply_ry16<BIT>(v, (f2){c, c}, (f2){s, s}); }

  #pragma unroll 1
  for (int l = 0; l < NL; ++l) {
    const float* wl = w + l*NQ*3;

    // ---- cooperative precise trig: lane slot s computes sincosf(ang_s).
    // slots 0..11: RY theta for wire s; 12..15: phi phasor wires 11..8;
    // 16..19: omega phasor wires 3..0. (lanes >=20 duplicate slot 0.)
    float cv_s, sv_s;
    {
      int slot = (lane < 20) ? lane : 0;
      float ang;
      if (slot < 12)      ang = 0.5f * wl[slot*3 + 1];
      else if (slot < 16) ang = 0.5f * wl[(23 - slot)*3 + 0];
      else                ang = 0.5f * wl[(19 - slot)*3 + 2];
      sincosf(ang, &sv_s, &cv_s);
    }

    // ---- pass A: wires 11..8 (label bits 0..3)
    if (l > 0) {
      #pragma unroll
      for (int m = 0; m < 8; ++m) {
        float4 q4 = *(const float4*)(stb + baseA[m]);
        v[2*m]   = (f2){q4.x, q4.y};
        v[2*m+1] = (f2){q4.z, q4.w};
      }
    }
    {  // D_phi: zfull[j] = z01[j&3] * (z23[j>>2] incl. wA)
      f2 p0 = BC(12), p1 = BC(13), p2 = BC(14), p3 = BC(15);
      float fa = 0.f;
      #pragma unroll
      for (int k = 0; k < 8; ++k) fa += sg[k] * wl[(7-k)*3 + 0];
      float was, wac; sincosf(fa, &was, &wac);
      f2 wA = (f2){wac, was};
      f2 z01[4] = { cmulp(cj(p0), cj(p1)), cmulp(p0, cj(p1)),
                    cmulp(cj(p0), p1),     cmulp(p0, p1) };
      f2 w2m = cmulp(cj(p2), wA), w2p = cmulp(p2, wA);
      f2 z23[4] = { cmulp(w2m, cj(p3)), cmulp(w2p, cj(p3)),
                    cmulp(w2m, p3),     cmulp(w2p, p3) };
      #pragma unroll
      for (int j = 0; j < 16; ++j)
        v[j] = cmulp(cmulp(v[j], z01[j & 3]), z23[j >> 2]);
    }
    RYG(0,11) RYG(1,10) RYG(2,9) RYG(3,8)
    #pragma unroll
    for (int m = 0; m < 8; ++m)
      *(float4*)(stb + baseA[m]) =
          make_float4(v[2*m].x, v[2*m].y, v[2*m+1].x, v[2*m+1].y);
    __syncthreads();

    // ---- pass B: wires 7..4 (label bits 4..7); load phys14, store phys15
    #pragma unroll
    for (int m = 0; m < 8; ++m) {
      v[2*m]   = *(const f2*)(stb + baseB[m] + (2*m)*128);
      v[2*m+1] = *(const f2*)(stb + baseB[m] + (2*m+1)*128);
    }
    RYG(0,7) RYG(1,6) RYG(2,5) RYG(3,4)
    #pragma unroll
    for (int m = 0; m < 8; ++m) {
      *(f2*)(stb + baseB[m] + (2*m)*128)         = v[2*m];
      *(f2*)(stb + (baseB[m] ^ 8) + (2*m+1)*128) = v[2*m+1];
    }
    __syncthreads();

    // ---- pass C: wires 3..0 (label bits 8..11); load phys15
    #pragma unroll
    for (int j = 0; j < 16; ++j)
      v[j] = *(const f2*)(stb + baseC + j*2048);
    RYG(0,3) RYG(1,2) RYG(2,1) RYG(3,0)
    if (l < NL-1) {
      {  // D_om (skipped last layer: cannot affect |amp|^2)
        f2 q0 = BC(16), q1 = BC(17), q2 = BC(18), q3 = BC(19);
        float fc = 0.f;
        #pragma unroll
        for (int k = 0; k < 8; ++k) fc += sg[k] * wl[(11-k)*3 + 2];
        float wcs, wcc; sincosf(fc, &wcs, &wcc);
        f2 wC = (f2){wcc, wcs};
        f2 z01[4] = { cmulp(cj(q0), cj(q1)), cmulp(q0, cj(q1)),
                      cmulp(cj(q0), q1),     cmulp(q0, q1) };
        f2 w2m = cmulp(cj(q2), wC), w2p = cmulp(q2, wC);
        f2 z23[4] = { cmulp(w2m, cj(q3)), cmulp(w2p, cj(q3)),
                      cmulp(w2m, q3),     cmulp(w2p, q3) };
        #pragma unroll
        for (int j = 0; j < 16; ++j)
          v[j] = cmulp(cmulp(v[j], z01[j & 3]), z23[j >> 2]);
      }
      // store with CNOT fold: slot = gray(label), layout phys14;
      // high nibble of gray(label) = gray4(j)
      #pragma unroll
      for (int j = 0; j < 16; ++j) {
        const int g4 = (j ^ (j >> 1)) & 15;
        *(f2*)(stb + baseS[j & 1] + (g4 << 11)) = v[j];
      }
      __syncthreads();
    }
  }

  // ---- Epilogue: labels s = t | j<<8; post-CNOT wire0 = j3, wire1 = j2^j3.
  float a0 = 0.f, a1 = 0.f;
  #pragma unroll
  for (int j = 0; j < 16; ++j) {
    float pr = v[j].x*v[j].x + v[j].y*v[j].y;
    a0 += ((j >> 3) & 1) ? -pr : pr;
    a1 += (((j >> 2) ^ (j >> 3)) & 1) ? -pr : pr;
  }
  #pragma unroll
  for (int off = 32; off >= 1; off >>= 1) {
    a0 += __shfl_down(a0, off);
    a1 += __shfl_down(a1, off);
  }
  __syncthreads();                 // all LDS reads done before st reuse
  if ((t & 63) == 0) { st[(t >> 6)*2] = a0; st[(t >> 6)*2 + 1] = a1; }
  __syncthreads();
  if (t == 0) {
    out[b*2 + 0] = st[0] + st[2] + st[4] + st[6];
    out[b*2 + 1] = st[1] + st[3] + st[5] + st[7];
  }
}

extern "C" void kernel_launch(void* const* d_in, const int* in_sizes, int n_in,
                              void* d_out, int out_size, void* d_ws, size_t ws_size,
                              hipStream_t stream) {
  const float* x = (const float*)d_in[0];      // (B, 12) f32
  const float* w = (const float*)d_in[1];      // (6, 12, 3) f32
  float* out = (float*)d_out;                  // (B, 2) f32
  int B = in_sizes[0] / NQ;
  qsim12_kernel<<<B, TPB, 0, stream>>>(x, w, out);
}

// Round 12
// 144.090 us; speedup vs baseline: 1.0605x; 1.0605x over previous
//
#include <hip/hip_runtime.h>
#include <math.h>

#define NQ 12
#define DIM 4096
#define NL 6
#define TPB 256

typedef float f2 __attribute__((ext_vector_type(2)));

// ---------------------------------------------------------------------------
// R12 = R11 with __launch_bounds__(256,4) instead of (256,5).
// R11's (256,5) made the allocator clamp to 48 VGPR and spill to scratch
// (WRITE_SIZE 64 KB -> 15.7 MB, FETCH 0.3 -> 7.5 MB, kernel 96.9 -> 118 µs).
// With (256,4) the register allocator has room (R8 ran at 56 VGPR), and the
// 5th block/CU comes from the LDS limit alone: state-only LDS = 32768 B ->
// floor(160K/32K) = 5 blocks/CU = 20 waves, VGPR non-binding at ~56.
//
// Structure (verified R5/R7/R8/R11-correctness): logical-basis state, CNOT
// block = label->gray(label) folded into pass-C store addresses, phys14/
// phys15 GF(2) bank swizzles, 3 passes/layer (label bits 0-3/4-7/8-11 =
// wires 11-8/7-4/3-0), RZ/RY factoring (diagonals via two-level register
// z-tables, RY with real packed coefficients), wave-cooperative precise
// sincosf for the 20 uniform angles/layer + 2 per-thread (wA/wC),
// last-layer D_om skipped, epilogue signs wire0=j3, wire1=j2^j3.
// ---------------------------------------------------------------------------

__device__ __forceinline__ f2 pk_mul(f2 a, f2 b) {
  f2 d; asm("v_pk_mul_f32 %0, %1, %2" : "=v"(d) : "v"(a), "v"(b)); return d;
}
__device__ __forceinline__ f2 pk_fma(f2 a, f2 b, f2 c) {
  f2 d; asm("v_pk_fma_f32 %0, %1, %2, %3" : "=v"(d) : "v"(a), "v"(b), "v"(c)); return d;
}
// complex mul, both operands packed (re,im)  [verified R8]
__device__ __forceinline__ f2 cmulp(f2 a, f2 c) {
  f2 r1, d;
  asm("v_pk_mul_f32 %0, %1, %2 op_sel:[0,0] op_sel_hi:[0,1]"
      : "=v"(r1) : "v"(a), "v"(c));
  asm("v_pk_fma_f32 %0, %1, %2, %3 op_sel:[1,1,0] op_sel_hi:[1,0,1] neg_lo:[1,0,0]"
      : "=v"(d) : "v"(a), "v"(c), "v"(r1));
  return d;
}
__device__ __forceinline__ f2 cj(f2 a) { return (f2){a.x, -a.y}; }

// RY pair update: a' = c*a - s*b ; b' = s*a + c*b  [verified R8]
template<int BIT>
__device__ __forceinline__ void apply_ry16(f2 v[16], f2 cc, f2 ss) {
  #pragma unroll
  for (int j = 0; j < 16; ++j) {
    if (j & (1 << BIT)) continue;
    const int k = j | (1 << BIT);
    f2 a = v[j], b = v[k];
    f2 t1 = pk_mul(a, cc);
    f2 t2 = pk_mul(a, ss);
    f2 na; asm("v_pk_fma_f32 %0, %1, %2, %3 neg_lo:[1,0,0] neg_hi:[1,0,0]"
               : "=v"(na) : "v"(b), "v"(ss), "v"(t1));
    f2 nb = pk_fma(b, cc, t2);
    v[j] = na; v[k] = nb;
  }
}

__global__ __launch_bounds__(TPB, 4)
void qsim12_kernel(const float* __restrict__ x, const float* __restrict__ w,
                   float* __restrict__ out) {
  __shared__ __align__(16) float st[2*DIM];   // exactly 32 KB — sole LDS use

  const int t = threadIdx.x;
  const int b = blockIdx.x;
  char* stb = (char*)st;
  const int lane = t & 63;

  // Precomputed byte-address bases (verified R5/R7).
  int baseA[8], baseB[8];
  #pragma unroll
  for (int m = 0; m < 8; ++m) {
    baseA[m] = (t << 7) + (((2*m) ^ (t & 14)) << 3);                 // phys14, A b128
    baseB[m] = ((t >> 4) << 11) + ((((t & 15) ^ (2*m))) << 3);       // + j*128
  }
  const int baseC = ((t >> 4) << 7) + ((((t & 15) ^ ((t >> 4) & 15))) << 3);  // + j*2048
  const int G = t ^ (t >> 1);
  int baseS[2];
  #pragma unroll
  for (int par = 0; par < 2; ++par) {
    const int k8 = par << 3;
    baseS[par] = ((((G >> 4) & 15) ^ k8) << 7)
               + ((((G & 15) ^ ((G >> 4) & 14) ^ k8)) << 3);
  }
  // per-thread diagonal signs (0.5 factor folded in)
  float sg[8];
  #pragma unroll
  for (int k = 0; k < 8; ++k) sg[k] = ((t >> k) & 1) ? 0.5f : -0.5f;

  f2 v[16];

  // ---- Init: amp(label) = prod_w (bit? sin:cos) * (-i)^popcount(label).
  // Pass-A ownership: label = t*16+j. Precise sincosf (12, once per thread).
  {
    float cw[NQ], sw[NQ];
    #pragma unroll
    for (int q = 0; q < NQ; ++q) {
      float xv = 0.5f * x[b*NQ + q];
      sincosf(xv, &sw[q], &cw[q]);
    }
    float rhi = 1.f;
    #pragma unroll
    for (int k = 0; k < 8; ++k)
      rhi *= ((t >> k) & 1) ? sw[7-k] : cw[7-k];
    const int popt = __popc(t);
    #pragma unroll
    for (int j = 0; j < 16; ++j) {
      float r = rhi;
      #pragma unroll
      for (int m = 0; m < 4; ++m)
        r *= ((j >> m) & 1) ? sw[11-m] : cw[11-m];
      const int pj = (popt + __popc(j)) & 3;
      if      (pj == 0) v[j] = (f2){ r, 0.f};
      else if (pj == 1) v[j] = (f2){0.f, -r};
      else if (pj == 2) v[j] = (f2){-r, 0.f};
      else              v[j] = (f2){0.f,  r};
    }
  }

  // broadcast slot -> packed phasor / RY coeffs (cv_s,sv_s computed per layer)
  #define BC(S)  (f2){ __shfl(cv_s, (S)), __shfl(sv_s, (S)) }
  #define RYG(BIT, WQ)                                                \
    { float c = __shfl(cv_s, (WQ)), s = __shfl(sv_s, (WQ));           \
      apply_ry16<BIT>(v, (f2){c, c}, (f2){s, s}); }

  #pragma unroll 1
  for (int l = 0; l < NL; ++l) {
    const float* wl = w + l*NQ*3;

    // ---- cooperative precise trig: lane slot s computes sincosf(ang_s).
    // slots 0..11: RY theta for wire s; 12..15: phi phasor wires 11..8;
    // 16..19: omega phasor wires 3..0. (lanes >=20 duplicate slot 0.)
    float cv_s, sv_s;
    {
      int slot = (lane < 20) ? lane : 0;
      float ang;
      if (slot < 12)      ang = 0.5f * wl[slot*3 + 1];
      else if (slot < 16) ang = 0.5f * wl[(23 - slot)*3 + 0];
      else                ang = 0.5f * wl[(19 - slot)*3 + 2];
      sincosf(ang, &sv_s, &cv_s);
    }

    // ---- pass A: wires 11..8 (label bits 0..3)
    if (l > 0) {
      #pragma unroll
      for (int m = 0; m < 8; ++m) {
        float4 q4 = *(const float4*)(stb + baseA[m]);
        v[2*m]   = (f2){q4.x, q4.y};
        v[2*m+1] = (f2){q4.z, q4.w};
      }
    }
    {  // D_phi: zfull[j] = z01[j&3] * (z23[j>>2] incl. wA)
      f2 p0 = BC(12), p1 = BC(13), p2 = BC(14), p3 = BC(15);
      float fa = 0.f;
      #pragma unroll
      for (int k = 0; k < 8; ++k) fa += sg[k] * wl[(7-k)*3 + 0];
      float was, wac; sincosf(fa, &was, &wac);
      f2 wA = (f2){wac, was};
      f2 z01[4] = { cmulp(cj(p0), cj(p1)), cmulp(p0, cj(p1)),
                    cmulp(cj(p0), p1),     cmulp(p0, p1) };
      f2 w2m = cmulp(cj(p2), wA), w2p = cmulp(p2, wA);
      f2 z23[4] = { cmulp(w2m, cj(p3)), cmulp(w2p, cj(p3)),
                    cmulp(w2m, p3),     cmulp(w2p, p3) };
      #pragma unroll
      for (int j = 0; j < 16; ++j)
        v[j] = cmulp(cmulp(v[j], z01[j & 3]), z23[j >> 2]);
    }
    RYG(0,11) RYG(1,10) RYG(2,9) RYG(3,8)
    #pragma unroll
    for (int m = 0; m < 8; ++m)
      *(float4*)(stb + baseA[m]) =
          make_float4(v[2*m].x, v[2*m].y, v[2*m+1].x, v[2*m+1].y);
    __syncthreads();

    // ---- pass B: wires 7..4 (label bits 4..7); load phys14, store phys15
    #pragma unroll
    for (int m = 0; m < 8; ++m) {
      v[2*m]   = *(const f2*)(stb + baseB[m] + (2*m)*128);
      v[2*m+1] = *(const f2*)(stb + baseB[m] + (2*m+1)*128);
    }
    RYG(0,7) RYG(1,6) RYG(2,5) RYG(3,4)
    #pragma unroll
    for (int m = 0; m < 8; ++m) {
      *(f2*)(stb + baseB[m] + (2*m)*128)         = v[2*m];
      *(f2*)(stb + (baseB[m] ^ 8) + (2*m+1)*128) = v[2*m+1];
    }
    __syncthreads();

    // ---- pass C: wires 3..0 (label bits 8..11); load phys15
    #pragma unroll
    for (int j = 0; j < 16; ++j)
      v[j] = *(const f2*)(stb + baseC + j*2048);
    RYG(0,3) RYG(1,2) RYG(2,1) RYG(3,0)
    if (l < NL-1) {
      {  // D_om (skipped last layer: cannot affect |amp|^2)
        f2 q0 = BC(16), q1 = BC(17), q2 = BC(18), q3 = BC(19);
        float fc = 0.f;
        #pragma unroll
        for (int k = 0; k < 8; ++k) fc += sg[k] * wl[(11-k)*3 + 2];
        float wcs, wcc; sincosf(fc, &wcs, &wcc);
        f2 wC = (f2){wcc, wcs};
        f2 z01[4] = { cmulp(cj(q0), cj(q1)), cmulp(q0, cj(q1)),
                      cmulp(cj(q0), q1),     cmulp(q0, q1) };
        f2 w2m = cmulp(cj(q2), wC), w2p = cmulp(q2, wC);
        f2 z23[4] = { cmulp(w2m, cj(q3)), cmulp(w2p, cj(q3)),
                      cmulp(w2m, q3),     cmulp(w2p, q3) };
        #pragma unroll
        for (int j = 0; j < 16; ++j)
          v[j] = cmulp(cmulp(v[j], z01[j & 3]), z23[j >> 2]);
      }
      // store with CNOT fold: slot = gray(label), layout phys14;
      // high nibble of gray(label) = gray4(j)
      #pragma unroll
      for (int j = 0; j < 16; ++j) {
        const int g4 = (j ^ (j >> 1)) & 15;
        *(f2*)(stb + baseS[j & 1] + (g4 << 11)) = v[j];
      }
      __syncthreads();
    }
  }

  // ---- Epilogue: labels s = t | j<<8; post-CNOT wire0 = j3, wire1 = j2^j3.
  float a0 = 0.f, a1 = 0.f;
  #pragma unroll
  for (int j = 0; j < 16; ++j) {
    float pr = v[j].x*v[j].x + v[j].y*v[j].y;
    a0 += ((j >> 3) & 1) ? -pr : pr;
    a1 += (((j >> 2) ^ (j >> 3)) & 1) ? -pr : pr;
  }
  #pragma unroll
  for (int off = 32; off >= 1; off >>= 1) {
    a0 += __shfl_down(a0, off);
    a1 += __shfl_down(a1, off);
  }
  __syncthreads();                 // all LDS reads done before st reuse
  if ((t & 63) == 0) { st[(t >> 6)*2] = a0; st[(t >> 6)*2 + 1] = a1; }
  __syncthreads();
  if (t == 0) {
    out[b*2 + 0] = st[0] + st[2] + st[4] + st[6];
    out[b*2 + 1] = st[1] + st[3] + st[5] + st[7];
  }
}

extern "C" void kernel_launch(void* const* d_in, const int* in_sizes, int n_in,
                              void* d_out, int out_size, void* d_ws, size_t ws_size,
                              hipStream_t stream) {
  const float* x = (const float*)d_in[0];      // (B, 12) f32
  const float* w = (const float*)d_in[1];      // (6, 12, 3) f32
  float* out = (float*)d_out;                  // (B, 2) f32
  int B = in_sizes[0] / NQ;
  qsim12_kernel<<<B, TPB, 0, stream>>>(x, w, out);
}